// Round 6
// baseline (413.713 us; speedup 1.0000x reference)
//
#include <hip/hip_runtime.h>
#include <hip/hip_bf16.h>
#include <cstdint>
#include <cstddef>

#define NN 30000
#define NE 480000
#define NG 128
#define DIN 128
#define DH 256
#define NC 60
#define NB 118  // scan blocks: ceil(30000/256)

typedef _Float16 f16x8 __attribute__((ext_vector_type(8)));
typedef _Float16 half4_t __attribute__((ext_vector_type(4)));
typedef float f32x4 __attribute__((ext_vector_type(4)));

// ---------------- CSR build ----------------
__global__ void k_count(const int* __restrict__ dst, int* __restrict__ icnt) {
    int e = blockIdx.x * blockDim.x + threadIdx.x;
    if (e < NE) atomicAdd(&icnt[dst[e]], 1);
}

__global__ void k_dinv(const int* __restrict__ icnt, float* __restrict__ dinv) {
    int v = blockIdx.x * blockDim.x + threadIdx.x;
    if (v < NN) dinv[v] = rsqrtf((float)(icnt[v] + 1));  // +1 self-loop
}

// scan stage 1: per-block sums of icnt
__global__ __launch_bounds__(256) void k_scan1(const int* __restrict__ icnt, int* __restrict__ psum) {
    __shared__ int ws[4];
    int i = blockIdx.x * 256 + threadIdx.x;
    int lane = threadIdx.x & 63, wv = threadIdx.x >> 6;
    int v = (i < NN) ? icnt[i] : 0;
    #pragma unroll
    for (int off = 32; off > 0; off >>= 1) v += __shfl_down(v, off, 64);
    if (lane == 0) ws[wv] = v;
    __syncthreads();
    if (threadIdx.x == 0) psum[blockIdx.x] = ws[0] + ws[1] + ws[2] + ws[3];
}

// scan stage 2: exclusive scan of NB partial sums (1 wave)
__global__ __launch_bounds__(64) void k_scan2(const int* __restrict__ psum, int* __restrict__ poff) {
    int lane = threadIdx.x;
    int carry = 0;
    for (int base = 0; base < NB; base += 64) {
        int i = base + lane;
        int v = (i < NB) ? psum[i] : 0;
        int s = v;
        #pragma unroll
        for (int off = 1; off < 64; off <<= 1) {
            int n = __shfl_up(s, off, 64);
            if (lane >= off) s += n;
        }
        if (i < NB) poff[i] = carry + s - v;
        carry += __shfl(s, 63, 64);
    }
}

// scan stage 3: row_ptr = poff[b] + exclusive within block
__global__ __launch_bounds__(256) void k_scan3(const int* __restrict__ icnt, const int* __restrict__ poff,
                                               int* __restrict__ row_ptr) {
    __shared__ int ws[4];
    int i = blockIdx.x * 256 + threadIdx.x;
    int lane = threadIdx.x & 63, wv = threadIdx.x >> 6;
    int v = (i < NN) ? icnt[i] : 0;
    int s = v;
    #pragma unroll
    for (int off = 1; off < 64; off <<= 1) {
        int n = __shfl_up(s, off, 64);
        if (lane >= off) s += n;
    }
    if (lane == 63) ws[wv] = s;
    __syncthreads();
    int add = 0;
    for (int j = 0; j < wv; j++) add += ws[j];
    if (i < NN) row_ptr[i] = poff[blockIdx.x] + add + s - v;
    if (blockIdx.x == 0 && threadIdx.x == 0) row_ptr[NN] = NE;
}

__global__ void k_fill(const int* __restrict__ ei, const float* __restrict__ dinv,
                       const int* __restrict__ row_ptr, int* __restrict__ cursor,
                       int* __restrict__ csr_src, float* __restrict__ csr_w) {
    int e = blockIdx.x * blockDim.x + threadIdx.x;
    if (e >= NE) return;
    int s = ei[e];        // edge_index[0]
    int d = ei[NE + e];   // edge_index[1]
    int pos = row_ptr[d] + atomicAdd(&cursor[d], 1);
    csr_src[pos] = s;
    csr_w[pos] = dinv[s] * dinv[d];
}

// ---------------- W: fp32 -> fp16 ----------------
__global__ void k_w2h(const float* __restrict__ W, _Float16* __restrict__ Wh, int n) {
    int i = blockIdx.x * blockDim.x + threadIdx.x;
    if (i < n) Wh[i] = (_Float16)W[i];
}

// ---------------- x: fp32 -> fp16 plane ----------------
__global__ void k_x2h(const float* __restrict__ x, _Float16* __restrict__ xh, int n4) {
    int i = blockIdx.x * blockDim.x + threadIdx.x;
    if (i < n4) {
        float4 v = ((const float4*)x)[i];
        half4_t o;
        o[0] = (_Float16)v.x; o[1] = (_Float16)v.y;
        o[2] = (_Float16)v.z; o[3] = (_Float16)v.w;
        ((half4_t*)xh)[i] = o;
    }
}

// ---------------- slab-partitioned aggregation ----------------
// u[v] = sum_e w_e*in[src_e] + dinv[v]^2*in[v]; fp16 plane in/out, fp32 accumulate.
// Feature dim split into NSLAB slabs of 64; slab = blockIdx.x & (NSLAB-1) so the
// round-robin workgroup->XCD dispatch pins each slab's 30000*64*2B = 3.84 MB
// working set into one XCD's 4 MB L2 (locality heuristic only, not correctness).
// wave = one node x one slab; lane = feature (2B loads, 128 B/wave gathers).
template<int D, int NSLAB, int SHIFT>
__global__ __launch_bounds__(256) void k_agg(const _Float16* __restrict__ tin,
                      _Float16* __restrict__ tout,
                      const int* __restrict__ row_ptr, const int* __restrict__ csr_src,
                      const float* __restrict__ csr_w, const float* __restrict__ dinv) {
    int bx = blockIdx.x;
    int slab = bx & (NSLAB - 1);
    int node = (bx >> SHIFT) * 4 + (threadIdx.x >> 6);  // NN % 4 == 0
    int lane = threadIdx.x & 63;
    const _Float16* base = tin + slab * 64 + lane;
    float acc = 0.f;
    int beg = row_ptr[node], end = row_ptr[node + 1];
    int e = beg;
    for (; e + 8 <= end; e += 8) {
        int s[8]; float w[8];
        #pragma unroll
        for (int j = 0; j < 8; j++) { s[j] = csr_src[e + j]; w[j] = csr_w[e + j]; }
        float r[8];
        #pragma unroll
        for (int j = 0; j < 8; j++) r[j] = (float)base[(size_t)s[j] * D];
        #pragma unroll
        for (int j = 0; j < 8; j++) acc = fmaf(w[j], r[j], acc);
    }
    for (; e < end; e++) {
        acc = fmaf(csr_w[e], (float)base[(size_t)csr_src[e] * D], acc);
    }
    float dv = dinv[node];
    acc = fmaf(dv * dv, (float)base[(size_t)node * D], acc);
    tout[(size_t)node * D + slab * 64 + lane] = (_Float16)acc;
}

// ---------------- fp16 MFMA GEMM: C[M x 256] = relu(A * W^T + bias) ----------------
// A fp16 [M x K]; W fp16 [256 x K] (K-contiguous, NT).
// Block 256 threads (4 waves), tile BM=128 x BN=64, BK=32. Wave = 64x32 = 4x2 tiles of 16x16.
// LDS rows padded to 40 halves (80 B) to break bank aliasing on ds_read_b128.
// F16_OUT: store result as fp16 plane (feeds next agg); else fp32 (feeds pool).
template<int K, bool F16_OUT>
__global__ __launch_bounds__(256) void k_gemm(const _Float16* __restrict__ A,
        const _Float16* __restrict__ Wh,
        const float* __restrict__ bias, float* __restrict__ C,
        _Float16* __restrict__ Cb, int M) {
    __shared__ _Float16 lsA[128 * 40];
    __shared__ _Float16 lsB[64 * 40];
    int t = threadIdx.x;
    int bm = blockIdx.x * 128;
    int bn = blockIdx.y * 64;
    int lane = t & 63, wv = t >> 6;
    int wm = (wv & 1) * 64;       // wave m-offset in block
    int wn = (wv >> 1) * 32;      // wave n-offset in block
    int lm = lane & 15, q = lane >> 4;
    // staging roles
    int r4 = t >> 2;   // 0..63
    int c4 = t & 3;    // 16B chunk (8 halves)
    int ra0 = bm + r4;       if (ra0 >= M) ra0 = M - 1;
    int ra1 = bm + 64 + r4;  if (ra1 >= M) ra1 = M - 1;
    int rb  = bn + r4;       // < 256 always

    f32x4 acc[4][2];
    #pragma unroll
    for (int i = 0; i < 4; i++)
        #pragma unroll
        for (int j = 0; j < 2; j++) acc[i][j] = (f32x4){0.f, 0.f, 0.f, 0.f};

    for (int k0 = 0; k0 < K; k0 += 32) {
        size_t ko = (size_t)k0 + c4 * 8;
        uint4 a0 = *(const uint4*)(A + (size_t)ra0 * K + ko);
        uint4 a1 = *(const uint4*)(A + (size_t)ra1 * K + ko);
        uint4 bh = *(const uint4*)(Wh + (size_t)rb * K + ko);
        __syncthreads();  // previous tile fully consumed
        *(uint4*)&lsA[r4 * 40 + c4 * 8] = a0;
        *(uint4*)&lsA[(64 + r4) * 40 + c4 * 8] = a1;
        *(uint4*)&lsB[r4 * 40 + c4 * 8] = bh;
        __syncthreads();  // tile staged
        f16x8 bf[2];
        #pragma unroll
        for (int nt = 0; nt < 2; nt++) {
            bf[nt] = *(const f16x8*)&lsB[(wn + nt * 16 + lm) * 40 + q * 8];
        }
        #pragma unroll
        for (int mt = 0; mt < 4; mt++) {
            f16x8 af = *(const f16x8*)&lsA[(wm + mt * 16 + lm) * 40 + q * 8];
            #pragma unroll
            for (int nt = 0; nt < 2; nt++) {
                acc[mt][nt] = __builtin_amdgcn_mfma_f32_16x16x32_f16(af, bf[nt], acc[mt][nt], 0, 0, 0);
            }
        }
    }
    // epilogue: C/D layout col = lane&15, row = q*4 + r
    #pragma unroll
    for (int mt = 0; mt < 4; mt++) {
        #pragma unroll
        for (int nt = 0; nt < 2; nt++) {
            int col = bn + wn + nt * 16 + lm;
            float bv = bias[col];
            #pragma unroll
            for (int r = 0; r < 4; r++) {
                int row = bm + wm + mt * 16 + q * 4 + r;
                if (row < M) {
                    float v = fmaxf(acc[mt][nt][r] + bv, 0.f);
                    if constexpr (F16_OUT) {
                        Cb[(size_t)row * 256 + col] = (_Float16)v;
                    } else {
                        C[(size_t)row * 256 + col] = v;
                    }
                }
            }
        }
    }
}

// ---------------- pool stage 1: chunked segmented sum (batch sorted) ----------------
__global__ __launch_bounds__(256) void k_pool(const float* __restrict__ h, const int* __restrict__ batch,
                       float* __restrict__ sums) {
    int f = threadIdx.x;
    int r0 = blockIdx.x * 64;
    int r1 = min(r0 + 64, NN);
    float acc = 0.f;
    int cur = batch[r0];
    for (int r = r0; r < r1; r++) {
        int g = batch[r];  // uniform across block; L1 broadcast
        if (g != cur) {
            atomicAdd(&sums[cur * DH + f], acc);
            acc = 0.f;
            cur = g;
        }
        acc += h[(size_t)r * DH + f];
    }
    atomicAdd(&sums[cur * DH + f], acc);
}

// ---------------- FC: out[G x 60] = (sums[g]/cnt) @ Wfc[60 x 256]^T + bfc ----------------
__global__ __launch_bounds__(64) void k_fc(const float* __restrict__ sums, const int* __restrict__ batch,
                    const float* __restrict__ Wfc, const float* __restrict__ bfc,
                    float* __restrict__ out) {
    __shared__ float p[DH];
    int g = blockIdx.x;
    int t = threadIdx.x;
    // count rows of graph g (batch sorted): redundant binary search per thread
    int lo = 0, hi = NN;
    while (lo < hi) { int mid = (lo + hi) >> 1; if (batch[mid] < g) lo = mid + 1; else hi = mid; }
    int start = lo;
    hi = NN;
    while (lo < hi) { int mid = (lo + hi) >> 1; if (batch[mid] < g + 1) lo = mid + 1; else hi = mid; }
    int cnt = lo - start;
    float inv = (cnt > 0) ? 1.f / (float)cnt : 0.f;
    for (int i = t; i < DH; i += 64) p[i] = sums[g * DH + i] * inv;
    __syncthreads();
    if (t < NC) {
        float a = bfc[t];
        for (int k = 0; k < DH; k++) a = fmaf(p[k], Wfc[t * DH + k], a);
        out[g * NC + t] = a;
    }
}

extern "C" void kernel_launch(void* const* d_in, const int* in_sizes, int n_in,
                              void* d_out, int out_size, void* d_ws, size_t ws_size,
                              hipStream_t stream) {
    const float* x     = (const float*)d_in[0];
    const int*   ei    = (const int*)d_in[1];
    const int*   batch = (const int*)d_in[2];
    const float* W1 = (const float*)d_in[3];
    const float* b1 = (const float*)d_in[4];
    const float* W2 = (const float*)d_in[5];
    const float* b2 = (const float*)d_in[6];
    const float* W3 = (const float*)d_in[7];
    const float* b3 = (const float*)d_in[8];
    const float* Wfc = (const float*)d_in[9];
    const float* bfc = (const float*)d_in[10];
    float* out = (float*)d_out;

    char* wp = (char*)d_ws;
    auto alloc = [&](size_t bytes) {
        char* p = wp;
        wp += (bytes + 511) & ~(size_t)511;
        return (void*)p;
    };
    int*   icnt    = (int*)alloc((size_t)NN * 4);
    int*   row_ptr = (int*)alloc((size_t)(NN + 1) * 4);
    int*   cursor  = (int*)alloc((size_t)NN * 4);
    int*   psum    = (int*)alloc((size_t)NB * 4);
    int*   poff    = (int*)alloc((size_t)NB * 4);
    int*   csr_src = (int*)alloc((size_t)NE * 4);
    float* csr_w   = (float*)alloc((size_t)NE * 4);
    float* dinv    = (float*)alloc((size_t)NN * 4);
    _Float16* xh   = (_Float16*)alloc((size_t)NN * DIN * 2);
    _Float16* tb   = (_Float16*)alloc((size_t)NN * DH * 2);   // agg output
    _Float16* hb   = (_Float16*)alloc((size_t)NN * DH * 2);   // gemm fp16 output
    float* hbuf    = (float*)alloc((size_t)NN * DH * 4);      // final layer fp32
    _Float16* w1h = (_Float16*)alloc((size_t)DH * DIN * 2);
    _Float16* w2h = (_Float16*)alloc((size_t)DH * DH * 2);
    _Float16* w3h = (_Float16*)alloc((size_t)DH * DH * 2);
    float* sums    = (float*)alloc((size_t)NG * DH * 4);

    hipMemsetAsync(icnt, 0, (size_t)NN * 4, stream);
    hipMemsetAsync(cursor, 0, (size_t)NN * 4, stream);
    hipMemsetAsync(sums, 0, (size_t)NG * DH * 4, stream);

    k_count<<<(NE + 255) / 256, 256, 0, stream>>>(ei + NE, icnt);
    k_dinv<<<(NN + 255) / 256, 256, 0, stream>>>(icnt, dinv);
    k_scan1<<<NB, 256, 0, stream>>>(icnt, psum);
    k_scan2<<<1, 64, 0, stream>>>(psum, poff);
    k_scan3<<<NB, 256, 0, stream>>>(icnt, poff, row_ptr);
    k_fill<<<(NE + 255) / 256, 256, 0, stream>>>(ei, dinv, row_ptr, cursor, csr_src, csr_w);

    k_w2h<<<(DH * DIN + 255) / 256, 256, 0, stream>>>(W1, w1h, DH * DIN);
    k_w2h<<<(DH * DH + 255) / 256, 256, 0, stream>>>(W2, w2h, DH * DH);
    k_w2h<<<(DH * DH + 255) / 256, 256, 0, stream>>>(W3, w3h, DH * DH);
    k_x2h<<<(NN * DIN / 4 + 255) / 256, 256, 0, stream>>>(x, xh, NN * DIN / 4);

    dim3 gemm_grid((NN + 127) / 128, 4);

    // all layers: h_l = relu((A.h_{l-1}) W^T + b)  [linearity reorder]
    // D=128: 2 slabs (grid = NN/4*2); D=256: 4 slabs (grid = NN/4*4)
    k_agg<128, 2, 1><<<NN / 4 * 2, 256, 0, stream>>>(xh, tb, row_ptr, csr_src, csr_w, dinv);
    k_gemm<128, true><<<gemm_grid, 256, 0, stream>>>(tb, w1h, b1, nullptr, hb, NN);
    k_agg<256, 4, 2><<<NN / 4 * 4, 256, 0, stream>>>(hb, tb, row_ptr, csr_src, csr_w, dinv);
    k_gemm<256, true><<<gemm_grid, 256, 0, stream>>>(tb, w2h, b2, nullptr, hb, NN);
    k_agg<256, 4, 2><<<NN / 4 * 4, 256, 0, stream>>>(hb, tb, row_ptr, csr_src, csr_w, dinv);
    k_gemm<256, false><<<gemm_grid, 256, 0, stream>>>(tb, w3h, b3, hbuf, nullptr, NN);

    k_pool<<<(NN + 63) / 64, 256, 0, stream>>>(hbuf, batch, sums);
    k_fc<<<NG, 64, 0, stream>>>(sums, batch, Wfc, bfc, out);
}

// Round 7
// 375.670 us; speedup vs baseline: 1.1013x; 1.1013x over previous
//
#include <hip/hip_runtime.h>
#include <hip/hip_bf16.h>
#include <cstdint>
#include <cstddef>

#define NN 30000
#define NE 480000
#define NG 128
#define DIN 128
#define DH 256
#define NC 60
#define NB 118  // scan blocks: ceil(30000/256)

typedef _Float16 f16x8 __attribute__((ext_vector_type(8)));
typedef _Float16 half4_t __attribute__((ext_vector_type(4)));
typedef float f32x4 __attribute__((ext_vector_type(4)));

// ---------------- CSR build ----------------
__global__ void k_count(const int* __restrict__ dst, int* __restrict__ icnt) {
    int e = blockIdx.x * blockDim.x + threadIdx.x;
    if (e < NE) atomicAdd(&icnt[dst[e]], 1);
}

__global__ void k_dinv(const int* __restrict__ icnt, float* __restrict__ dinv) {
    int v = blockIdx.x * blockDim.x + threadIdx.x;
    if (v < NN) dinv[v] = rsqrtf((float)(icnt[v] + 1));  // +1 self-loop
}

// scan stage 1: per-block sums of icnt
__global__ __launch_bounds__(256) void k_scan1(const int* __restrict__ icnt, int* __restrict__ psum) {
    __shared__ int ws[4];
    int i = blockIdx.x * 256 + threadIdx.x;
    int lane = threadIdx.x & 63, wv = threadIdx.x >> 6;
    int v = (i < NN) ? icnt[i] : 0;
    #pragma unroll
    for (int off = 32; off > 0; off >>= 1) v += __shfl_down(v, off, 64);
    if (lane == 0) ws[wv] = v;
    __syncthreads();
    if (threadIdx.x == 0) psum[blockIdx.x] = ws[0] + ws[1] + ws[2] + ws[3];
}

// scan stage 2: exclusive scan of NB partial sums (1 wave)
__global__ __launch_bounds__(64) void k_scan2(const int* __restrict__ psum, int* __restrict__ poff) {
    int lane = threadIdx.x;
    int carry = 0;
    for (int base = 0; base < NB; base += 64) {
        int i = base + lane;
        int v = (i < NB) ? psum[i] : 0;
        int s = v;
        #pragma unroll
        for (int off = 1; off < 64; off <<= 1) {
            int n = __shfl_up(s, off, 64);
            if (lane >= off) s += n;
        }
        if (i < NB) poff[i] = carry + s - v;
        carry += __shfl(s, 63, 64);
    }
}

// scan stage 3: row_ptr = poff[b] + exclusive within block
__global__ __launch_bounds__(256) void k_scan3(const int* __restrict__ icnt, const int* __restrict__ poff,
                                               int* __restrict__ row_ptr) {
    __shared__ int ws[4];
    int i = blockIdx.x * 256 + threadIdx.x;
    int lane = threadIdx.x & 63, wv = threadIdx.x >> 6;
    int v = (i < NN) ? icnt[i] : 0;
    int s = v;
    #pragma unroll
    for (int off = 1; off < 64; off <<= 1) {
        int n = __shfl_up(s, off, 64);
        if (lane >= off) s += n;
    }
    if (lane == 63) ws[wv] = s;
    __syncthreads();
    int add = 0;
    for (int j = 0; j < wv; j++) add += ws[j];
    if (i < NN) row_ptr[i] = poff[blockIdx.x] + add + s - v;
    if (blockIdx.x == 0 && threadIdx.x == 0) row_ptr[NN] = NE;
}

__global__ void k_fill(const int* __restrict__ ei, const float* __restrict__ dinv,
                       const int* __restrict__ row_ptr, int* __restrict__ cursor,
                       int* __restrict__ csr_src, float* __restrict__ csr_w) {
    int e = blockIdx.x * blockDim.x + threadIdx.x;
    if (e >= NE) return;
    int s = ei[e];        // edge_index[0]
    int d = ei[NE + e];   // edge_index[1]
    int pos = row_ptr[d] + atomicAdd(&cursor[d], 1);
    csr_src[pos] = s;
    csr_w[pos] = dinv[s] * dinv[d];
}

// ---------------- W: fp32 -> fp16 ----------------
__global__ void k_w2h(const float* __restrict__ W, _Float16* __restrict__ Wh, int n) {
    int i = blockIdx.x * blockDim.x + threadIdx.x;
    if (i < n) Wh[i] = (_Float16)W[i];
}

// ---------------- x: fp32 -> fp16 plane ----------------
__global__ void k_x2h(const float* __restrict__ x, _Float16* __restrict__ xh, int n4) {
    int i = blockIdx.x * blockDim.x + threadIdx.x;
    if (i < n4) {
        float4 v = ((const float4*)x)[i];
        half4_t o;
        o[0] = (_Float16)v.x; o[1] = (_Float16)v.y;
        o[2] = (_Float16)v.z; o[3] = (_Float16)v.w;
        ((half4_t*)xh)[i] = o;
    }
}

// ---------------- slab-partitioned aggregation, 4-edge-parallel ----------------
// u[v] = sum_e w_e*in[src_e] + dinv[v]^2*in[v]; fp16 plane in/out, fp32 accumulate.
// Feature dim split into NSLAB slabs of 64; slab = blockIdx.x & (NSLAB-1) so the
// round-robin workgroup->XCD dispatch pins each slab's 30000*64*2B = 3.84 MB
// working set into one XCD's 4 MB L2 (locality heuristic — R6 measured FETCH 229->43 MB).
// Wave = one node x one slab. Lanes: sub = lane>>4 (4 edges in flight),
// fl = lane&15 (16 x half4 = full 64-wide slab) -> 512 B per gather instruction.
// shfl_xor(16),(32) folds the 4 edge groups; sub==0 stores.
template<int D, int NSLAB, int SHIFT>
__global__ __launch_bounds__(256) void k_agg(const _Float16* __restrict__ tin,
                      _Float16* __restrict__ tout,
                      const int* __restrict__ row_ptr, const int* __restrict__ csr_src,
                      const float* __restrict__ csr_w, const float* __restrict__ dinv) {
    int bx = blockIdx.x;
    int slab = bx & (NSLAB - 1);
    int node = (bx >> SHIFT) * 4 + (threadIdx.x >> 6);  // NN % 4 == 0
    int lane = threadIdx.x & 63;
    int sub = lane >> 4;   // edge sub-slot 0..3
    int fl = lane & 15;    // feature quad within slab
    const _Float16* base = tin + slab * 64 + fl * 4;
    float acc[4] = {0.f, 0.f, 0.f, 0.f};
    int beg = row_ptr[node], end = row_ptr[node + 1];
    int e = beg;
    // unroll x2: 8 edges in flight (both groups fully valid)
    for (; e + 8 <= end; e += 8) {
        int s0 = csr_src[e + sub];
        int s1 = csr_src[e + 4 + sub];
        float w0 = csr_w[e + sub];
        float w1 = csr_w[e + 4 + sub];
        half4_t r0 = *(const half4_t*)(base + (size_t)s0 * D);
        half4_t r1 = *(const half4_t*)(base + (size_t)s1 * D);
        #pragma unroll
        for (int u = 0; u < 4; u++) acc[u] = fmaf(w0, (float)r0[u], fmaf(w1, (float)r1[u], acc[u]));
    }
    // masked tail, 4 edges per round
    for (; e < end; e += 4) {
        int ee = e + sub;
        bool valid = ee < end;
        int s0 = valid ? csr_src[ee] : node;
        float w0 = valid ? csr_w[ee] : 0.f;
        half4_t r0 = *(const half4_t*)(base + (size_t)s0 * D);
        #pragma unroll
        for (int u = 0; u < 4; u++) acc[u] = fmaf(w0, (float)r0[u], acc[u]);
    }
    // fold the 4 edge groups
    #pragma unroll
    for (int u = 0; u < 4; u++) {
        acc[u] += __shfl_xor(acc[u], 16, 64);
        acc[u] += __shfl_xor(acc[u], 32, 64);
    }
    // self-loop (after fold: added once)
    float dv = dinv[node];
    float sw = dv * dv;
    half4_t rv = *(const half4_t*)(base + (size_t)node * D);
    #pragma unroll
    for (int u = 0; u < 4; u++) acc[u] = fmaf(sw, (float)rv[u], acc[u]);
    if (sub == 0) {
        half4_t o;
        #pragma unroll
        for (int u = 0; u < 4; u++) o[u] = (_Float16)acc[u];
        *(half4_t*)(tout + (size_t)node * D + slab * 64 + fl * 4) = o;
    }
}

// ---------------- fp16 MFMA GEMM: C[M x 256] = relu(A * W^T + bias) ----------------
// A fp16 [M x K]; W fp16 [256 x K] (K-contiguous, NT).
// Block 256 threads (4 waves), tile BM=128 x BN=64, BK=32. Wave = 64x32 = 4x2 tiles of 16x16.
// LDS rows padded to 40 halves (80 B) to break bank aliasing on ds_read_b128.
// F16_OUT: store result as fp16 plane (feeds next agg); else fp32 (feeds pool).
template<int K, bool F16_OUT>
__global__ __launch_bounds__(256) void k_gemm(const _Float16* __restrict__ A,
        const _Float16* __restrict__ Wh,
        const float* __restrict__ bias, float* __restrict__ C,
        _Float16* __restrict__ Cb, int M) {
    __shared__ _Float16 lsA[128 * 40];
    __shared__ _Float16 lsB[64 * 40];
    int t = threadIdx.x;
    int bm = blockIdx.x * 128;
    int bn = blockIdx.y * 64;
    int lane = t & 63, wv = t >> 6;
    int wm = (wv & 1) * 64;       // wave m-offset in block
    int wn = (wv >> 1) * 32;      // wave n-offset in block
    int lm = lane & 15, q = lane >> 4;
    // staging roles
    int r4 = t >> 2;   // 0..63
    int c4 = t & 3;    // 16B chunk (8 halves)
    int ra0 = bm + r4;       if (ra0 >= M) ra0 = M - 1;
    int ra1 = bm + 64 + r4;  if (ra1 >= M) ra1 = M - 1;
    int rb  = bn + r4;       // < 256 always

    f32x4 acc[4][2];
    #pragma unroll
    for (int i = 0; i < 4; i++)
        #pragma unroll
        for (int j = 0; j < 2; j++) acc[i][j] = (f32x4){0.f, 0.f, 0.f, 0.f};

    for (int k0 = 0; k0 < K; k0 += 32) {
        size_t ko = (size_t)k0 + c4 * 8;
        uint4 a0 = *(const uint4*)(A + (size_t)ra0 * K + ko);
        uint4 a1 = *(const uint4*)(A + (size_t)ra1 * K + ko);
        uint4 bh = *(const uint4*)(Wh + (size_t)rb * K + ko);
        __syncthreads();  // previous tile fully consumed
        *(uint4*)&lsA[r4 * 40 + c4 * 8] = a0;
        *(uint4*)&lsA[(64 + r4) * 40 + c4 * 8] = a1;
        *(uint4*)&lsB[r4 * 40 + c4 * 8] = bh;
        __syncthreads();  // tile staged
        f16x8 bf[2];
        #pragma unroll
        for (int nt = 0; nt < 2; nt++) {
            bf[nt] = *(const f16x8*)&lsB[(wn + nt * 16 + lm) * 40 + q * 8];
        }
        #pragma unroll
        for (int mt = 0; mt < 4; mt++) {
            f16x8 af = *(const f16x8*)&lsA[(wm + mt * 16 + lm) * 40 + q * 8];
            #pragma unroll
            for (int nt = 0; nt < 2; nt++) {
                acc[mt][nt] = __builtin_amdgcn_mfma_f32_16x16x32_f16(af, bf[nt], acc[mt][nt], 0, 0, 0);
            }
        }
    }
    // epilogue: C/D layout col = lane&15, row = q*4 + r
    #pragma unroll
    for (int mt = 0; mt < 4; mt++) {
        #pragma unroll
        for (int nt = 0; nt < 2; nt++) {
            int col = bn + wn + nt * 16 + lm;
            float bv = bias[col];
            #pragma unroll
            for (int r = 0; r < 4; r++) {
                int row = bm + wm + mt * 16 + q * 4 + r;
                if (row < M) {
                    float v = fmaxf(acc[mt][nt][r] + bv, 0.f);
                    if constexpr (F16_OUT) {
                        Cb[(size_t)row * 256 + col] = (_Float16)v;
                    } else {
                        C[(size_t)row * 256 + col] = v;
                    }
                }
            }
        }
    }
}

// ---------------- pool stage 1: chunked segmented sum (batch sorted) ----------------
__global__ __launch_bounds__(256) void k_pool(const float* __restrict__ h, const int* __restrict__ batch,
                       float* __restrict__ sums) {
    int f = threadIdx.x;
    int r0 = blockIdx.x * 64;
    int r1 = min(r0 + 64, NN);
    float acc = 0.f;
    int cur = batch[r0];
    for (int r = r0; r < r1; r++) {
        int g = batch[r];  // uniform across block; L1 broadcast
        if (g != cur) {
            atomicAdd(&sums[cur * DH + f], acc);
            acc = 0.f;
            cur = g;
        }
        acc += h[(size_t)r * DH + f];
    }
    atomicAdd(&sums[cur * DH + f], acc);
}

// ---------------- FC: out[G x 60] = (sums[g]/cnt) @ Wfc[60 x 256]^T + bfc ----------------
__global__ __launch_bounds__(64) void k_fc(const float* __restrict__ sums, const int* __restrict__ batch,
                    const float* __restrict__ Wfc, const float* __restrict__ bfc,
                    float* __restrict__ out) {
    __shared__ float p[DH];
    int g = blockIdx.x;
    int t = threadIdx.x;
    // count rows of graph g (batch sorted): redundant binary search per thread
    int lo = 0, hi = NN;
    while (lo < hi) { int mid = (lo + hi) >> 1; if (batch[mid] < g) lo = mid + 1; else hi = mid; }
    int start = lo;
    hi = NN;
    while (lo < hi) { int mid = (lo + hi) >> 1; if (batch[mid] < g + 1) lo = mid + 1; else hi = mid; }
    int cnt = lo - start;
    float inv = (cnt > 0) ? 1.f / (float)cnt : 0.f;
    for (int i = t; i < DH; i += 64) p[i] = sums[g * DH + i] * inv;
    __syncthreads();
    if (t < NC) {
        float a = bfc[t];
        for (int k = 0; k < DH; k++) a = fmaf(p[k], Wfc[t * DH + k], a);
        out[g * NC + t] = a;
    }
}

extern "C" void kernel_launch(void* const* d_in, const int* in_sizes, int n_in,
                              void* d_out, int out_size, void* d_ws, size_t ws_size,
                              hipStream_t stream) {
    const float* x     = (const float*)d_in[0];
    const int*   ei    = (const int*)d_in[1];
    const int*   batch = (const int*)d_in[2];
    const float* W1 = (const float*)d_in[3];
    const float* b1 = (const float*)d_in[4];
    const float* W2 = (const float*)d_in[5];
    const float* b2 = (const float*)d_in[6];
    const float* W3 = (const float*)d_in[7];
    const float* b3 = (const float*)d_in[8];
    const float* Wfc = (const float*)d_in[9];
    const float* bfc = (const float*)d_in[10];
    float* out = (float*)d_out;

    char* wp = (char*)d_ws;
    auto alloc = [&](size_t bytes) {
        char* p = wp;
        wp += (bytes + 511) & ~(size_t)511;
        return (void*)p;
    };
    int*   icnt    = (int*)alloc((size_t)NN * 4);
    int*   row_ptr = (int*)alloc((size_t)(NN + 1) * 4);
    int*   cursor  = (int*)alloc((size_t)NN * 4);
    int*   psum    = (int*)alloc((size_t)NB * 4);
    int*   poff    = (int*)alloc((size_t)NB * 4);
    int*   csr_src = (int*)alloc((size_t)NE * 4);
    float* csr_w   = (float*)alloc((size_t)NE * 4);
    float* dinv    = (float*)alloc((size_t)NN * 4);
    _Float16* xh   = (_Float16*)alloc((size_t)NN * DIN * 2);
    _Float16* tb   = (_Float16*)alloc((size_t)NN * DH * 2);   // agg output
    _Float16* hb   = (_Float16*)alloc((size_t)NN * DH * 2);   // gemm fp16 output
    float* hbuf    = (float*)alloc((size_t)NN * DH * 4);      // final layer fp32
    _Float16* w1h = (_Float16*)alloc((size_t)DH * DIN * 2);
    _Float16* w2h = (_Float16*)alloc((size_t)DH * DH * 2);
    _Float16* w3h = (_Float16*)alloc((size_t)DH * DH * 2);
    float* sums    = (float*)alloc((size_t)NG * DH * 4);

    hipMemsetAsync(icnt, 0, (size_t)NN * 4, stream);
    hipMemsetAsync(cursor, 0, (size_t)NN * 4, stream);
    hipMemsetAsync(sums, 0, (size_t)NG * DH * 4, stream);

    k_count<<<(NE + 255) / 256, 256, 0, stream>>>(ei + NE, icnt);
    k_dinv<<<(NN + 255) / 256, 256, 0, stream>>>(icnt, dinv);
    k_scan1<<<NB, 256, 0, stream>>>(icnt, psum);
    k_scan2<<<1, 64, 0, stream>>>(psum, poff);
    k_scan3<<<NB, 256, 0, stream>>>(icnt, poff, row_ptr);
    k_fill<<<(NE + 255) / 256, 256, 0, stream>>>(ei, dinv, row_ptr, cursor, csr_src, csr_w);

    k_w2h<<<(DH * DIN + 255) / 256, 256, 0, stream>>>(W1, w1h, DH * DIN);
    k_w2h<<<(DH * DH + 255) / 256, 256, 0, stream>>>(W2, w2h, DH * DH);
    k_w2h<<<(DH * DH + 255) / 256, 256, 0, stream>>>(W3, w3h, DH * DH);
    k_x2h<<<(NN * DIN / 4 + 255) / 256, 256, 0, stream>>>(x, xh, NN * DIN / 4);

    dim3 gemm_grid((NN + 127) / 128, 4);

    // all layers: h_l = relu((A.h_{l-1}) W^T + b)  [linearity reorder]
    // D=128: 2 slabs (grid = NN/4*2); D=256: 4 slabs (grid = NN/4*4)
    k_agg<128, 2, 1><<<NN / 4 * 2, 256, 0, stream>>>(xh, tb, row_ptr, csr_src, csr_w, dinv);
    k_gemm<128, true><<<gemm_grid, 256, 0, stream>>>(tb, w1h, b1, nullptr, hb, NN);
    k_agg<256, 4, 2><<<NN / 4 * 4, 256, 0, stream>>>(hb, tb, row_ptr, csr_src, csr_w, dinv);
    k_gemm<256, true><<<gemm_grid, 256, 0, stream>>>(tb, w2h, b2, nullptr, hb, NN);
    k_agg<256, 4, 2><<<NN / 4 * 4, 256, 0, stream>>>(hb, tb, row_ptr, csr_src, csr_w, dinv);
    k_gemm<256, false><<<gemm_grid, 256, 0, stream>>>(tb, w3h, b3, hbuf, nullptr, NN);

    k_pool<<<(NN + 63) / 64, 256, 0, stream>>>(hbuf, batch, sums);
    k_fc<<<NG, 64, 0, stream>>>(sums, batch, Wfc, bfc, out);
}

// Round 8
// 333.923 us; speedup vs baseline: 1.2389x; 1.1250x over previous
//
#include <hip/hip_runtime.h>
#include <hip/hip_bf16.h>
#include <cstdint>
#include <cstddef>
#include <type_traits>

#define NN 30000
#define NE 480000
#define NG 128
#define DIN 128
#define DH 256
#define NC 60
#define NB 118  // scan blocks: ceil(30000/256)

typedef _Float16 f16x8 __attribute__((ext_vector_type(8)));
typedef _Float16 half4_t __attribute__((ext_vector_type(4)));
typedef _Float16 half2_t __attribute__((ext_vector_type(2)));
typedef float f32x4 __attribute__((ext_vector_type(4)));

// ---------------- CSR build ----------------
__global__ void k_count(const int* __restrict__ dst, int* __restrict__ icnt) {
    int e = blockIdx.x * blockDim.x + threadIdx.x;
    if (e < NE) atomicAdd(&icnt[dst[e]], 1);
}

__global__ void k_dinv(const int* __restrict__ icnt, float* __restrict__ dinv) {
    int v = blockIdx.x * blockDim.x + threadIdx.x;
    if (v < NN) dinv[v] = rsqrtf((float)(icnt[v] + 1));  // +1 self-loop
}

// scan stage 1: per-block sums of icnt
__global__ __launch_bounds__(256) void k_scan1(const int* __restrict__ icnt, int* __restrict__ psum) {
    __shared__ int ws[4];
    int i = blockIdx.x * 256 + threadIdx.x;
    int lane = threadIdx.x & 63, wv = threadIdx.x >> 6;
    int v = (i < NN) ? icnt[i] : 0;
    #pragma unroll
    for (int off = 32; off > 0; off >>= 1) v += __shfl_down(v, off, 64);
    if (lane == 0) ws[wv] = v;
    __syncthreads();
    if (threadIdx.x == 0) psum[blockIdx.x] = ws[0] + ws[1] + ws[2] + ws[3];
}

// scan stage 2: exclusive scan of NB partial sums (1 wave)
__global__ __launch_bounds__(64) void k_scan2(const int* __restrict__ psum, int* __restrict__ poff) {
    int lane = threadIdx.x;
    int carry = 0;
    for (int base = 0; base < NB; base += 64) {
        int i = base + lane;
        int v = (i < NB) ? psum[i] : 0;
        int s = v;
        #pragma unroll
        for (int off = 1; off < 64; off <<= 1) {
            int n = __shfl_up(s, off, 64);
            if (lane >= off) s += n;
        }
        if (i < NB) poff[i] = carry + s - v;
        carry += __shfl(s, 63, 64);
    }
}

// scan stage 3: row_ptr = poff[b] + exclusive within block
__global__ __launch_bounds__(256) void k_scan3(const int* __restrict__ icnt, const int* __restrict__ poff,
                                               int* __restrict__ row_ptr) {
    __shared__ int ws[4];
    int i = blockIdx.x * 256 + threadIdx.x;
    int lane = threadIdx.x & 63, wv = threadIdx.x >> 6;
    int v = (i < NN) ? icnt[i] : 0;
    int s = v;
    #pragma unroll
    for (int off = 1; off < 64; off <<= 1) {
        int n = __shfl_up(s, off, 64);
        if (lane >= off) s += n;
    }
    if (lane == 63) ws[wv] = s;
    __syncthreads();
    int add = 0;
    for (int j = 0; j < wv; j++) add += ws[j];
    if (i < NN) row_ptr[i] = poff[blockIdx.x] + add + s - v;
    if (blockIdx.x == 0 && threadIdx.x == 0) row_ptr[NN] = NE;
}

__global__ void k_fill(const int* __restrict__ ei, const float* __restrict__ dinv,
                       const int* __restrict__ row_ptr, int* __restrict__ cursor,
                       int* __restrict__ csr_src, float* __restrict__ csr_w) {
    int e = blockIdx.x * blockDim.x + threadIdx.x;
    if (e >= NE) return;
    int s = ei[e];        // edge_index[0]
    int d = ei[NE + e];   // edge_index[1]
    int pos = row_ptr[d] + atomicAdd(&cursor[d], 1);
    csr_src[pos] = s;
    csr_w[pos] = dinv[s] * dinv[d];
}

// ---------------- W: fp32 -> fp16 ----------------
__global__ void k_w2h(const float* __restrict__ W, _Float16* __restrict__ Wh, int n) {
    int i = blockIdx.x * blockDim.x + threadIdx.x;
    if (i < n) Wh[i] = (_Float16)W[i];
}

// ---------------- x: fp32 -> fp16 plane ----------------
__global__ void k_x2h(const float* __restrict__ x, _Float16* __restrict__ xh, int n4) {
    int i = blockIdx.x * blockDim.x + threadIdx.x;
    if (i < n4) {
        float4 v = ((const float4*)x)[i];
        half4_t o;
        o[0] = (_Float16)v.x; o[1] = (_Float16)v.y;
        o[2] = (_Float16)v.z; o[3] = (_Float16)v.w;
        ((half4_t*)xh)[i] = o;
    }
}

// ---------------- aggregation: u[v] = sum_e w_e*in[src_e] + dinv[v]^2*in[v] ----------------
// fp16 plane in/out, fp32 accumulate. One wave per node, full row (lane = feature/V),
// wave-uniform edge metadata (compiles to scalar loads + broadcast). Unroll tiers 16/8/1
// for 16 outstanding 512B row gathers in the main tier (latency-bound regime).
template<int D>
__global__ __launch_bounds__(256) void k_agg(const _Float16* __restrict__ tin,
                      _Float16* __restrict__ tout,
                      const int* __restrict__ row_ptr, const int* __restrict__ csr_src,
                      const float* __restrict__ csr_w, const float* __restrict__ dinv) {
    constexpr int V = D / 64;
    using vec_t = std::conditional_t<V == 4, half4_t, half2_t>;
    int node = blockIdx.x * 4 + (threadIdx.x >> 6);
    int lane = threadIdx.x & 63;
    const _Float16* base = tin + lane * V;
    float acc[V];
    #pragma unroll
    for (int u = 0; u < V; u++) acc[u] = 0.f;
    int beg = row_ptr[node], end = row_ptr[node + 1];
    int e = beg;
    for (; e + 16 <= end; e += 16) {
        int s[16]; float w[16];
        #pragma unroll
        for (int j = 0; j < 16; j++) { s[j] = csr_src[e + j]; w[j] = csr_w[e + j]; }
        vec_t r[16];
        #pragma unroll
        for (int j = 0; j < 16; j++) r[j] = *(const vec_t*)(base + (size_t)s[j] * D);
        #pragma unroll
        for (int j = 0; j < 16; j++)
            #pragma unroll
            for (int u = 0; u < V; u++) acc[u] = fmaf(w[j], (float)r[j][u], acc[u]);
    }
    for (; e + 8 <= end; e += 8) {
        int s[8]; float w[8];
        #pragma unroll
        for (int j = 0; j < 8; j++) { s[j] = csr_src[e + j]; w[j] = csr_w[e + j]; }
        vec_t r[8];
        #pragma unroll
        for (int j = 0; j < 8; j++) r[j] = *(const vec_t*)(base + (size_t)s[j] * D);
        #pragma unroll
        for (int j = 0; j < 8; j++)
            #pragma unroll
            for (int u = 0; u < V; u++) acc[u] = fmaf(w[j], (float)r[j][u], acc[u]);
    }
    for (; e < end; e++) {
        int s0 = csr_src[e];
        float w0 = csr_w[e];
        vec_t r0 = *(const vec_t*)(base + (size_t)s0 * D);
        #pragma unroll
        for (int u = 0; u < V; u++) acc[u] = fmaf(w0, (float)r0[u], acc[u]);
    }
    float dv = dinv[node];
    float sw = dv * dv;
    vec_t rv = *(const vec_t*)(base + (size_t)node * D);
    #pragma unroll
    for (int u = 0; u < V; u++) acc[u] = fmaf(sw, (float)rv[u], acc[u]);
    vec_t o;
    #pragma unroll
    for (int u = 0; u < V; u++) o[u] = (_Float16)acc[u];
    *(vec_t*)(tout + (size_t)node * D + lane * V) = o;
}

// ---------------- fp16 MFMA GEMM: C[M x 256] = relu(A * W^T + bias), fp16 out ----------------
// A fp16 [M x K]; W fp16 [256 x K] (K-contiguous, NT).
// Block 256 threads (4 waves), tile BM=128 x BN=64, BK=32. Wave = 64x32 = 4x2 tiles of 16x16.
// LDS rows padded to 40 halves (80 B) to break bank aliasing on ds_read_b128.
template<int K>
__global__ __launch_bounds__(256) void k_gemm(const _Float16* __restrict__ A,
        const _Float16* __restrict__ Wh,
        const float* __restrict__ bias, _Float16* __restrict__ Cb, int M) {
    __shared__ _Float16 lsA[128 * 40];
    __shared__ _Float16 lsB[64 * 40];
    int t = threadIdx.x;
    int bm = blockIdx.x * 128;
    int bn = blockIdx.y * 64;
    int lane = t & 63, wv = t >> 6;
    int wm = (wv & 1) * 64;       // wave m-offset in block
    int wn = (wv >> 1) * 32;      // wave n-offset in block
    int lm = lane & 15, q = lane >> 4;
    // staging roles
    int r4 = t >> 2;   // 0..63
    int c4 = t & 3;    // 16B chunk (8 halves)
    int ra0 = bm + r4;       if (ra0 >= M) ra0 = M - 1;
    int ra1 = bm + 64 + r4;  if (ra1 >= M) ra1 = M - 1;
    int rb  = bn + r4;       // < 256 always

    f32x4 acc[4][2];
    #pragma unroll
    for (int i = 0; i < 4; i++)
        #pragma unroll
        for (int j = 0; j < 2; j++) acc[i][j] = (f32x4){0.f, 0.f, 0.f, 0.f};

    for (int k0 = 0; k0 < K; k0 += 32) {
        size_t ko = (size_t)k0 + c4 * 8;
        uint4 a0 = *(const uint4*)(A + (size_t)ra0 * K + ko);
        uint4 a1 = *(const uint4*)(A + (size_t)ra1 * K + ko);
        uint4 bh = *(const uint4*)(Wh + (size_t)rb * K + ko);
        __syncthreads();  // previous tile fully consumed
        *(uint4*)&lsA[r4 * 40 + c4 * 8] = a0;
        *(uint4*)&lsA[(64 + r4) * 40 + c4 * 8] = a1;
        *(uint4*)&lsB[r4 * 40 + c4 * 8] = bh;
        __syncthreads();  // tile staged
        f16x8 bf[2];
        #pragma unroll
        for (int nt = 0; nt < 2; nt++) {
            bf[nt] = *(const f16x8*)&lsB[(wn + nt * 16 + lm) * 40 + q * 8];
        }
        #pragma unroll
        for (int mt = 0; mt < 4; mt++) {
            f16x8 af = *(const f16x8*)&lsA[(wm + mt * 16 + lm) * 40 + q * 8];
            #pragma unroll
            for (int nt = 0; nt < 2; nt++) {
                acc[mt][nt] = __builtin_amdgcn_mfma_f32_16x16x32_f16(af, bf[nt], acc[mt][nt], 0, 0, 0);
            }
        }
    }
    // epilogue: C/D layout col = lane&15, row = q*4 + r
    #pragma unroll
    for (int mt = 0; mt < 4; mt++) {
        #pragma unroll
        for (int nt = 0; nt < 2; nt++) {
            int col = bn + wn + nt * 16 + lm;
            float bv = bias[col];
            #pragma unroll
            for (int r = 0; r < 4; r++) {
                int row = bm + wm + mt * 16 + q * 4 + r;
                if (row < M) {
                    float v = fmaxf(acc[mt][nt][r] + bv, 0.f);
                    Cb[(size_t)row * 256 + col] = (_Float16)v;
                }
            }
        }
    }
}

// ---------------- pool stage 1: chunked segmented sum (batch sorted), fp16 in ----------------
__global__ __launch_bounds__(256) void k_pool(const _Float16* __restrict__ h, const int* __restrict__ batch,
                       float* __restrict__ sums) {
    int f = threadIdx.x;
    int r0 = blockIdx.x * 64;
    int r1 = min(r0 + 64, NN);
    float acc = 0.f;
    int cur = batch[r0];
    for (int r = r0; r < r1; r++) {
        int g = batch[r];  // uniform across block; L1 broadcast
        if (g != cur) {
            atomicAdd(&sums[cur * DH + f], acc);
            acc = 0.f;
            cur = g;
        }
        acc += (float)h[(size_t)r * DH + f];
    }
    atomicAdd(&sums[cur * DH + f], acc);
}

// ---------------- FC: out[G x 60] = (sums[g]/cnt) @ Wfc[60 x 256]^T + bfc ----------------
__global__ __launch_bounds__(64) void k_fc(const float* __restrict__ sums, const int* __restrict__ batch,
                    const float* __restrict__ Wfc, const float* __restrict__ bfc,
                    float* __restrict__ out) {
    __shared__ float p[DH];
    int g = blockIdx.x;
    int t = threadIdx.x;
    // count rows of graph g (batch sorted): redundant binary search per thread
    int lo = 0, hi = NN;
    while (lo < hi) { int mid = (lo + hi) >> 1; if (batch[mid] < g) lo = mid + 1; else hi = mid; }
    int start = lo;
    hi = NN;
    while (lo < hi) { int mid = (lo + hi) >> 1; if (batch[mid] < g + 1) lo = mid + 1; else hi = mid; }
    int cnt = lo - start;
    float inv = (cnt > 0) ? 1.f / (float)cnt : 0.f;
    for (int i = t; i < DH; i += 64) p[i] = sums[g * DH + i] * inv;
    __syncthreads();
    if (t < NC) {
        float a = bfc[t];
        for (int k = 0; k < DH; k++) a = fmaf(p[k], Wfc[t * DH + k], a);
        out[g * NC + t] = a;
    }
}

extern "C" void kernel_launch(void* const* d_in, const int* in_sizes, int n_in,
                              void* d_out, int out_size, void* d_ws, size_t ws_size,
                              hipStream_t stream) {
    const float* x     = (const float*)d_in[0];
    const int*   ei    = (const int*)d_in[1];
    const int*   batch = (const int*)d_in[2];
    const float* W1 = (const float*)d_in[3];
    const float* b1 = (const float*)d_in[4];
    const float* W2 = (const float*)d_in[5];
    const float* b2 = (const float*)d_in[6];
    const float* W3 = (const float*)d_in[7];
    const float* b3 = (const float*)d_in[8];
    const float* Wfc = (const float*)d_in[9];
    const float* bfc = (const float*)d_in[10];
    float* out = (float*)d_out;

    char* wp = (char*)d_ws;
    auto alloc = [&](size_t bytes) {
        char* p = wp;
        wp += (bytes + 511) & ~(size_t)511;
        return (void*)p;
    };
    int*   icnt    = (int*)alloc((size_t)NN * 4);
    int*   row_ptr = (int*)alloc((size_t)(NN + 1) * 4);
    int*   cursor  = (int*)alloc((size_t)NN * 4);
    int*   psum    = (int*)alloc((size_t)NB * 4);
    int*   poff    = (int*)alloc((size_t)NB * 4);
    int*   csr_src = (int*)alloc((size_t)NE * 4);
    float* csr_w   = (float*)alloc((size_t)NE * 4);
    float* dinv    = (float*)alloc((size_t)NN * 4);
    _Float16* xh   = (_Float16*)alloc((size_t)NN * DIN * 2);
    _Float16* tb   = (_Float16*)alloc((size_t)NN * DH * 2);   // agg output
    _Float16* hb   = (_Float16*)alloc((size_t)NN * DH * 2);   // gemm fp16 output
    _Float16* w1h = (_Float16*)alloc((size_t)DH * DIN * 2);
    _Float16* w2h = (_Float16*)alloc((size_t)DH * DH * 2);
    _Float16* w3h = (_Float16*)alloc((size_t)DH * DH * 2);
    float* sums    = (float*)alloc((size_t)NG * DH * 4);

    hipMemsetAsync(icnt, 0, (size_t)NN * 4, stream);
    hipMemsetAsync(cursor, 0, (size_t)NN * 4, stream);
    hipMemsetAsync(sums, 0, (size_t)NG * DH * 4, stream);

    k_count<<<(NE + 255) / 256, 256, 0, stream>>>(ei + NE, icnt);
    k_dinv<<<(NN + 255) / 256, 256, 0, stream>>>(icnt, dinv);
    k_scan1<<<NB, 256, 0, stream>>>(icnt, psum);
    k_scan2<<<1, 64, 0, stream>>>(psum, poff);
    k_scan3<<<NB, 256, 0, stream>>>(icnt, poff, row_ptr);
    k_fill<<<(NE + 255) / 256, 256, 0, stream>>>(ei, dinv, row_ptr, cursor, csr_src, csr_w);

    k_w2h<<<(DH * DIN + 255) / 256, 256, 0, stream>>>(W1, w1h, DH * DIN);
    k_w2h<<<(DH * DH + 255) / 256, 256, 0, stream>>>(W2, w2h, DH * DH);
    k_w2h<<<(DH * DH + 255) / 256, 256, 0, stream>>>(W3, w3h, DH * DH);
    k_x2h<<<(NN * DIN / 4 + 255) / 256, 256, 0, stream>>>(x, xh, NN * DIN / 4);

    dim3 gemm_grid((NN + 127) / 128, 4);

    // all layers: h_l = relu((A.h_{l-1}) W^T + b)  [linearity reorder]
    k_agg<128><<<NN / 4, 256, 0, stream>>>(xh, tb, row_ptr, csr_src, csr_w, dinv);
    k_gemm<128><<<gemm_grid, 256, 0, stream>>>(tb, w1h, b1, hb, NN);
    k_agg<256><<<NN / 4, 256, 0, stream>>>(hb, tb, row_ptr, csr_src, csr_w, dinv);
    k_gemm<256><<<gemm_grid, 256, 0, stream>>>(tb, w2h, b2, hb, NN);
    k_agg<256><<<NN / 4, 256, 0, stream>>>(hb, tb, row_ptr, csr_src, csr_w, dinv);
    k_gemm<256><<<gemm_grid, 256, 0, stream>>>(tb, w3h, b3, hb, NN);

    k_pool<<<(NN + 63) / 64, 256, 0, stream>>>(hb, batch, sums);
    k_fc<<<NG, 64, 0, stream>>>(sums, batch, Wfc, bfc, out);
}

// Round 9
// 320.505 us; speedup vs baseline: 1.2908x; 1.0419x over previous
//
#include <hip/hip_runtime.h>
#include <hip/hip_bf16.h>
#include <cstdint>
#include <cstddef>
#include <type_traits>

#define NN 30000
#define NE 480000
#define NG 128
#define DIN 128
#define DH 256
#define NC 60
#define NB 118  // scan blocks: ceil(30000/256)

typedef _Float16 f16x8 __attribute__((ext_vector_type(8)));
typedef _Float16 half4_t __attribute__((ext_vector_type(4)));
typedef _Float16 half2_t __attribute__((ext_vector_type(2)));
typedef float f32x4 __attribute__((ext_vector_type(4)));

// ---------------- fused preprocessing: edge-count + x->fp16 + W->fp16 ----------------
__global__ __launch_bounds__(256) void k_pre(const int* __restrict__ dst, int* __restrict__ icnt,
                     const float* __restrict__ x, _Float16* __restrict__ xh,
                     const float* __restrict__ W1, const float* __restrict__ W2,
                     const float* __restrict__ W3, _Float16* __restrict__ w1h,
                     _Float16* __restrict__ w2h, _Float16* __restrict__ w3h) {
    int i = blockIdx.x * 256 + threadIdx.x;
    if (i < NE) atomicAdd(&icnt[dst[i]], 1);
    if (i < NN * DIN / 4) {
        float4 v = ((const float4*)x)[i];
        half4_t o;
        o[0] = (_Float16)v.x; o[1] = (_Float16)v.y;
        o[2] = (_Float16)v.z; o[3] = (_Float16)v.w;
        ((half4_t*)xh)[i] = o;
    }
    if (i < DH * DIN) w1h[i] = (_Float16)W1[i];
    if (i < DH * DH) {
        w2h[i] = (_Float16)W2[i];
        w3h[i] = (_Float16)W3[i];
    }
}

// scan stage 1: per-block sums of icnt, fused with dinv = rsqrt(deg+1)
__global__ __launch_bounds__(256) void k_scan1(const int* __restrict__ icnt, int* __restrict__ psum,
                                               float* __restrict__ dinv) {
    __shared__ int ws[4];
    int i = blockIdx.x * 256 + threadIdx.x;
    int lane = threadIdx.x & 63, wv = threadIdx.x >> 6;
    int v = (i < NN) ? icnt[i] : 0;
    if (i < NN) dinv[i] = rsqrtf((float)(v + 1));
    #pragma unroll
    for (int off = 32; off > 0; off >>= 1) v += __shfl_down(v, off, 64);
    if (lane == 0) ws[wv] = v;
    __syncthreads();
    if (threadIdx.x == 0) psum[blockIdx.x] = ws[0] + ws[1] + ws[2] + ws[3];
}

// scan stage 2: exclusive scan of NB partial sums (1 wave)
__global__ __launch_bounds__(64) void k_scan2(const int* __restrict__ psum, int* __restrict__ poff) {
    int lane = threadIdx.x;
    int carry = 0;
    for (int base = 0; base < NB; base += 64) {
        int i = base + lane;
        int v = (i < NB) ? psum[i] : 0;
        int s = v;
        #pragma unroll
        for (int off = 1; off < 64; off <<= 1) {
            int n = __shfl_up(s, off, 64);
            if (lane >= off) s += n;
        }
        if (i < NB) poff[i] = carry + s - v;
        carry += __shfl(s, 63, 64);
    }
}

// scan stage 3: row_ptr = poff[b] + exclusive within block
__global__ __launch_bounds__(256) void k_scan3(const int* __restrict__ icnt, const int* __restrict__ poff,
                                               int* __restrict__ row_ptr) {
    __shared__ int ws[4];
    int i = blockIdx.x * 256 + threadIdx.x;
    int lane = threadIdx.x & 63, wv = threadIdx.x >> 6;
    int v = (i < NN) ? icnt[i] : 0;
    int s = v;
    #pragma unroll
    for (int off = 1; off < 64; off <<= 1) {
        int n = __shfl_up(s, off, 64);
        if (lane >= off) s += n;
    }
    if (lane == 63) ws[wv] = s;
    __syncthreads();
    int add = 0;
    for (int j = 0; j < wv; j++) add += ws[j];
    if (i < NN) row_ptr[i] = poff[blockIdx.x] + add + s - v;
    if (blockIdx.x == 0 && threadIdx.x == 0) row_ptr[NN] = NE;
}

__global__ void k_fill(const int* __restrict__ ei, const float* __restrict__ dinv,
                       const int* __restrict__ row_ptr, int* __restrict__ cursor,
                       int* __restrict__ csr_src, float* __restrict__ csr_w) {
    int e = blockIdx.x * blockDim.x + threadIdx.x;
    if (e >= NE) return;
    int s = ei[e];        // edge_index[0]
    int d = ei[NE + e];   // edge_index[1]
    int pos = row_ptr[d] + atomicAdd(&cursor[d], 1);
    csr_src[pos] = s;
    csr_w[pos] = dinv[s] * dinv[d];
}

// ---------------- aggregation: u[v] = sum_e w_e*in[src_e] + dinv[v]^2*in[v] ----------------
// fp16 plane in/out, fp32 accumulate. One wave per node, full row (lane = feature/V),
// wave-uniform edge metadata (scalar loads + broadcast). Unroll tiers 16/8/1.
template<int D>
__global__ __launch_bounds__(256) void k_agg(const _Float16* __restrict__ tin,
                      _Float16* __restrict__ tout,
                      const int* __restrict__ row_ptr, const int* __restrict__ csr_src,
                      const float* __restrict__ csr_w, const float* __restrict__ dinv) {
    constexpr int V = D / 64;
    using vec_t = std::conditional_t<V == 4, half4_t, half2_t>;
    int node = blockIdx.x * 4 + (threadIdx.x >> 6);
    int lane = threadIdx.x & 63;
    const _Float16* base = tin + lane * V;
    float acc[V];
    #pragma unroll
    for (int u = 0; u < V; u++) acc[u] = 0.f;
    int beg = row_ptr[node], end = row_ptr[node + 1];
    int e = beg;
    for (; e + 16 <= end; e += 16) {
        int s[16]; float w[16];
        #pragma unroll
        for (int j = 0; j < 16; j++) { s[j] = csr_src[e + j]; w[j] = csr_w[e + j]; }
        vec_t r[16];
        #pragma unroll
        for (int j = 0; j < 16; j++) r[j] = *(const vec_t*)(base + (size_t)s[j] * D);
        #pragma unroll
        for (int j = 0; j < 16; j++)
            #pragma unroll
            for (int u = 0; u < V; u++) acc[u] = fmaf(w[j], (float)r[j][u], acc[u]);
    }
    for (; e + 8 <= end; e += 8) {
        int s[8]; float w[8];
        #pragma unroll
        for (int j = 0; j < 8; j++) { s[j] = csr_src[e + j]; w[j] = csr_w[e + j]; }
        vec_t r[8];
        #pragma unroll
        for (int j = 0; j < 8; j++) r[j] = *(const vec_t*)(base + (size_t)s[j] * D);
        #pragma unroll
        for (int j = 0; j < 8; j++)
            #pragma unroll
            for (int u = 0; u < V; u++) acc[u] = fmaf(w[j], (float)r[j][u], acc[u]);
    }
    for (; e < end; e++) {
        int s0 = csr_src[e];
        float w0 = csr_w[e];
        vec_t r0 = *(const vec_t*)(base + (size_t)s0 * D);
        #pragma unroll
        for (int u = 0; u < V; u++) acc[u] = fmaf(w0, (float)r0[u], acc[u]);
    }
    float dv = dinv[node];
    float sw = dv * dv;
    vec_t rv = *(const vec_t*)(base + (size_t)node * D);
    #pragma unroll
    for (int u = 0; u < V; u++) acc[u] = fmaf(sw, (float)rv[u], acc[u]);
    vec_t o;
    #pragma unroll
    for (int u = 0; u < V; u++) o[u] = (_Float16)acc[u];
    *(vec_t*)(tout + (size_t)node * D + lane * V) = o;
}

// ---------------- fp16 MFMA GEMM: C[M x 256] = relu(A * W^T + bias), fp16 out ----------------
// A fp16 [M x K]; W fp16 [256 x K] (K-contiguous, NT).
// Block 256 threads (4 waves), tile BM=128 x BN=128, BK=32 (grid.y=2: A re-read 2x not 4x).
// Wave = 64x64 = 4x4 tiles of 16x16 (16 f32x4 accs). LDS rows padded to 40 halves.
template<int K>
__global__ __launch_bounds__(256) void k_gemm(const _Float16* __restrict__ A,
        const _Float16* __restrict__ Wh,
        const float* __restrict__ bias, _Float16* __restrict__ Cb, int M) {
    __shared__ _Float16 lsA[128 * 40];
    __shared__ _Float16 lsB[128 * 40];
    int t = threadIdx.x;
    int bm = blockIdx.x * 128;
    int bn = blockIdx.y * 128;
    int lane = t & 63, wv = t >> 6;
    int wm = (wv & 1) * 64;       // wave m-offset in block
    int wn = (wv >> 1) * 64;      // wave n-offset in block
    int lm = lane & 15, q = lane >> 4;
    // staging roles
    int r4 = t >> 2;   // 0..63
    int c4 = t & 3;    // 16B chunk (8 halves)
    int ra0 = bm + r4;       if (ra0 >= M) ra0 = M - 1;
    int ra1 = bm + 64 + r4;  if (ra1 >= M) ra1 = M - 1;
    int rb0 = bn + r4;       // < 256 always
    int rb1 = bn + 64 + r4;

    f32x4 acc[4][4];
    #pragma unroll
    for (int i = 0; i < 4; i++)
        #pragma unroll
        for (int j = 0; j < 4; j++) acc[i][j] = (f32x4){0.f, 0.f, 0.f, 0.f};

    for (int k0 = 0; k0 < K; k0 += 32) {
        size_t ko = (size_t)k0 + c4 * 8;
        uint4 a0 = *(const uint4*)(A + (size_t)ra0 * K + ko);
        uint4 a1 = *(const uint4*)(A + (size_t)ra1 * K + ko);
        uint4 b0 = *(const uint4*)(Wh + (size_t)rb0 * K + ko);
        uint4 b1 = *(const uint4*)(Wh + (size_t)rb1 * K + ko);
        __syncthreads();  // previous tile fully consumed
        *(uint4*)&lsA[r4 * 40 + c4 * 8] = a0;
        *(uint4*)&lsA[(64 + r4) * 40 + c4 * 8] = a1;
        *(uint4*)&lsB[r4 * 40 + c4 * 8] = b0;
        *(uint4*)&lsB[(64 + r4) * 40 + c4 * 8] = b1;
        __syncthreads();  // tile staged
        f16x8 bf[4];
        #pragma unroll
        for (int nt = 0; nt < 4; nt++) {
            bf[nt] = *(const f16x8*)&lsB[(wn + nt * 16 + lm) * 40 + q * 8];
        }
        #pragma unroll
        for (int mt = 0; mt < 4; mt++) {
            f16x8 af = *(const f16x8*)&lsA[(wm + mt * 16 + lm) * 40 + q * 8];
            #pragma unroll
            for (int nt = 0; nt < 4; nt++) {
                acc[mt][nt] = __builtin_amdgcn_mfma_f32_16x16x32_f16(af, bf[nt], acc[mt][nt], 0, 0, 0);
            }
        }
    }
    // epilogue: C/D layout col = lane&15, row = q*4 + r
    #pragma unroll
    for (int mt = 0; mt < 4; mt++) {
        #pragma unroll
        for (int nt = 0; nt < 4; nt++) {
            int col = bn + wn + nt * 16 + lm;
            float bv = bias[col];
            #pragma unroll
            for (int r = 0; r < 4; r++) {
                int row = bm + wm + mt * 16 + q * 4 + r;
                if (row < M) {
                    float v = fmaxf(acc[mt][nt][r] + bv, 0.f);
                    Cb[(size_t)row * 256 + col] = (_Float16)v;
                }
            }
        }
    }
}

// ---------------- pool stage 1: chunked segmented sum (batch sorted), fp16 in ----------------
__global__ __launch_bounds__(256) void k_pool(const _Float16* __restrict__ h, const int* __restrict__ batch,
                       float* __restrict__ sums) {
    int f = threadIdx.x;
    int r0 = blockIdx.x * 64;
    int r1 = min(r0 + 64, NN);
    float acc = 0.f;
    int cur = batch[r0];
    for (int r = r0; r < r1; r++) {
        int g = batch[r];  // uniform across block; L1 broadcast
        if (g != cur) {
            atomicAdd(&sums[cur * DH + f], acc);
            acc = 0.f;
            cur = g;
        }
        acc += (float)h[(size_t)r * DH + f];
    }
    atomicAdd(&sums[cur * DH + f], acc);
}

// ---------------- FC: out[G x 60] = (sums[g]/cnt) @ Wfc[60 x 256]^T + bfc ----------------
__global__ __launch_bounds__(64) void k_fc(const float* __restrict__ sums, const int* __restrict__ batch,
                    const float* __restrict__ Wfc, const float* __restrict__ bfc,
                    float* __restrict__ out) {
    __shared__ float p[DH];
    int g = blockIdx.x;
    int t = threadIdx.x;
    // count rows of graph g (batch sorted): redundant binary search per thread
    int lo = 0, hi = NN;
    while (lo < hi) { int mid = (lo + hi) >> 1; if (batch[mid] < g) lo = mid + 1; else hi = mid; }
    int start = lo;
    hi = NN;
    while (lo < hi) { int mid = (lo + hi) >> 1; if (batch[mid] < g + 1) lo = mid + 1; else hi = mid; }
    int cnt = lo - start;
    float inv = (cnt > 0) ? 1.f / (float)cnt : 0.f;
    for (int i = t; i < DH; i += 64) p[i] = sums[g * DH + i] * inv;
    __syncthreads();
    if (t < NC) {
        float a = bfc[t];
        for (int k = 0; k < DH; k++) a = fmaf(p[k], Wfc[t * DH + k], a);
        out[g * NC + t] = a;
    }
}

extern "C" void kernel_launch(void* const* d_in, const int* in_sizes, int n_in,
                              void* d_out, int out_size, void* d_ws, size_t ws_size,
                              hipStream_t stream) {
    const float* x     = (const float*)d_in[0];
    const int*   ei    = (const int*)d_in[1];
    const int*   batch = (const int*)d_in[2];
    const float* W1 = (const float*)d_in[3];
    const float* b1 = (const float*)d_in[4];
    const float* W2 = (const float*)d_in[5];
    const float* b2 = (const float*)d_in[6];
    const float* W3 = (const float*)d_in[7];
    const float* b3 = (const float*)d_in[8];
    const float* Wfc = (const float*)d_in[9];
    const float* bfc = (const float*)d_in[10];
    float* out = (float*)d_out;

    char* wp = (char*)d_ws;
    auto alloc = [&](size_t bytes) {
        char* p = wp;
        wp += (bytes + 511) & ~(size_t)511;
        return (void*)p;
    };
    int*   icnt    = (int*)alloc((size_t)NN * 4);
    int*   row_ptr = (int*)alloc((size_t)(NN + 1) * 4);
    int*   cursor  = (int*)alloc((size_t)NN * 4);
    int*   psum    = (int*)alloc((size_t)NB * 4);
    int*   poff    = (int*)alloc((size_t)NB * 4);
    int*   csr_src = (int*)alloc((size_t)NE * 4);
    float* csr_w   = (float*)alloc((size_t)NE * 4);
    float* dinv    = (float*)alloc((size_t)NN * 4);
    _Float16* xh   = (_Float16*)alloc((size_t)NN * DIN * 2);
    _Float16* tb   = (_Float16*)alloc((size_t)NN * DH * 2);   // agg output
    _Float16* hb   = (_Float16*)alloc((size_t)NN * DH * 2);   // gemm fp16 output
    _Float16* w1h = (_Float16*)alloc((size_t)DH * DIN * 2);
    _Float16* w2h = (_Float16*)alloc((size_t)DH * DH * 2);
    _Float16* w3h = (_Float16*)alloc((size_t)DH * DH * 2);
    float* sums    = (float*)alloc((size_t)NG * DH * 4);

    hipMemsetAsync(icnt, 0, (size_t)NN * 4, stream);
    hipMemsetAsync(cursor, 0, (size_t)NN * 4, stream);
    hipMemsetAsync(sums, 0, (size_t)NG * DH * 4, stream);

    // fused: edge degree count + x->fp16 + all W->fp16 (grid covers the max job)
    k_pre<<<(NN * DIN / 4 + 255) / 256, 256, 0, stream>>>(ei + NE, icnt, x, xh,
                                                          W1, W2, W3, w1h, w2h, w3h);
    k_scan1<<<NB, 256, 0, stream>>>(icnt, psum, dinv);
    k_scan2<<<1, 64, 0, stream>>>(psum, poff);
    k_scan3<<<NB, 256, 0, stream>>>(icnt, poff, row_ptr);
    k_fill<<<(NE + 255) / 256, 256, 0, stream>>>(ei, dinv, row_ptr, cursor, csr_src, csr_w);

    dim3 gemm_grid((NN + 127) / 128, 2);

    // all layers: h_l = relu((A.h_{l-1}) W^T + b)  [linearity reorder]
    k_agg<128><<<NN / 4, 256, 0, stream>>>(xh, tb, row_ptr, csr_src, csr_w, dinv);
    k_gemm<128><<<gemm_grid, 256, 0, stream>>>(tb, w1h, b1, hb, NN);
    k_agg<256><<<NN / 4, 256, 0, stream>>>(hb, tb, row_ptr, csr_src, csr_w, dinv);
    k_gemm<256><<<gemm_grid, 256, 0, stream>>>(tb, w2h, b2, hb, NN);
    k_agg<256><<<NN / 4, 256, 0, stream>>>(hb, tb, row_ptr, csr_src, csr_w, dinv);
    k_gemm<256><<<gemm_grid, 256, 0, stream>>>(tb, w3h, b3, hb, NN);

    k_pool<<<(NN + 63) / 64, 256, 0, stream>>>(hb, batch, sums);
    k_fc<<<NG, 64, 0, stream>>>(sums, batch, Wfc, bfc, out);
}